// Round 12
// baseline (390.560 us; speedup 1.0000x reference)
//
#include <hip/hip_runtime.h>
#include <cstddef>
#include <cstdint>

#define B_   2
#define S_   2048
#define HID  1024
#define NH_  16
#define NKV_ 4
#define DH_  64
#define ROWS (B_ * S_)   // 4096
#define NQKV 1536        // 1024 Q + 256 K + 256 V
#define QSCALE 0.18033688011112042f   // 0.125 * log2(e)  (exp2-domain softmax)

typedef __bf16 bf16_t;
typedef _Float16 f16_t;
typedef bf16_t bf16x8 __attribute__((ext_vector_type(8)));
typedef bf16_t bf16x4 __attribute__((ext_vector_type(4)));
typedef f16_t  f16x8  __attribute__((ext_vector_type(8)));
typedef f16_t  f16x4  __attribute__((ext_vector_type(4)));
typedef float  f32x4  __attribute__((ext_vector_type(4)));

typedef __attribute__((address_space(1))) const uint32_t gu32_t;
typedef __attribute__((address_space(3))) uint32_t lu32_t;

__device__ __forceinline__ void gl_lds16(const void* g, void* l) {
  __builtin_amdgcn_global_load_lds((gu32_t*)g, (lu32_t*)l, 16, 0, 0);
}

// ---------------------------------------------------------------------------
// prep_all (proven): fused cast + weight transpose + bias concat + RoPE LUT.
// ---------------------------------------------------------------------------
__global__ void prep_all(const float* __restrict__ hs,
                         const float* __restrict__ Wq, const float* __restrict__ Wk,
                         const float* __restrict__ Wv, const float* __restrict__ Wo,
                         const float* __restrict__ bq, const float* __restrict__ bk,
                         const float* __restrict__ bv,
                         bf16_t* __restrict__ hsb,
                         bf16_t* __restrict__ Wt, bf16_t* __restrict__ Wot,
                         float* __restrict__ ball, float2* __restrict__ lut)
{
  const int bid = blockIdx.x;
  if (bid < 2048) {                        // ---- cast hs -> bf16 ----
    const int i = (bid * 256 + threadIdx.x) * 8;
    float4 a = *(const float4*)(hs + i);
    float4 b = *(const float4*)(hs + i + 4);
    bf16x8 o;
    o[0]=(bf16_t)a.x; o[1]=(bf16_t)a.y; o[2]=(bf16_t)a.z; o[3]=(bf16_t)a.w;
    o[4]=(bf16_t)b.x; o[5]=(bf16_t)b.y; o[6]=(bf16_t)b.z; o[7]=(bf16_t)b.w;
    *(bf16x8*)(hsb + i) = o;
    return;
  }
  if (bid >= 4614) {                       // ---- RoPE LUT ----
    const int idx = (bid - 4614) * 256 + threadIdx.x;   // [0,65536)
    const int s = idx >> 5, j = idx & 31;
    const float L = 0.51905126482615037f;  // log2(1e5)/32
    const float ang = (float)s * exp2f(-L * (float)j);
    lut[idx] = make_float2(cosf(ang), sinf(ang));
    return;
  }
  if (bid >= 4608) {                       // ---- biases ----
    int i = (bid - 4608) * 256 + threadIdx.x;
    if (i < NQKV) ball[i] = (i < 1024) ? bq[i] : ((i < 1280) ? bk[i-1024] : bv[i-1280]);
    return;
  }
  const int wb = bid - 2048;               // ---- weight transpose ----
  const float* src; bf16_t* dst; int N, n0, k0;
  if (wb < 1024)      { src = Wq; dst = Wt;            N = 1024; int t = wb;      n0=(t&31)*32; k0=(t>>5)*32; }
  else if (wb < 1280) { src = Wk; dst = Wt + 1024*HID; N = 256;  int t = wb-1024; n0=(t&7)*32;  k0=(t>>3)*32; }
  else if (wb < 1536) { src = Wv; dst = Wt + 1280*HID; N = 256;  int t = wb-1280; n0=(t&7)*32;  k0=(t>>3)*32; }
  else                { src = Wo; dst = Wot;           N = 1024; int t = wb-1536; n0=(t&31)*32; k0=(t>>5)*32; }
  __shared__ bf16_t T[32][33];
  const int tx = threadIdx.x & 31, ty = threadIdx.x >> 5;
#pragma unroll
  for (int i = 0; i < 4; ++i)
    T[ty + i*8][tx] = (bf16_t)src[(size_t)(k0 + ty + i*8) * N + n0 + tx];
  __syncthreads();
#pragma unroll
  for (int i = 0; i < 4; ++i)
    dst[(size_t)(n0 + ty + i*8) * HID + k0 + tx] = T[tx][ty + i*8];
}

// ---------------------------------------------------------------------------
// gemm_qkv (R7-proven core): 128x64 GEMM + XCD swizzle + fused prep_kv
// epilogue.  Vimg built at 32-KEY granularity (64 images of [d in 64]
// [32 keys] per (b,kvh)): slot = (key32>>2) ^ (d&7).  Kimg unchanged
// (its [key][d] layout makes 32-key halves contiguous).
// ---------------------------------------------------------------------------
__global__ __launch_bounds__(256, 3) void gemm_qkv(
    const bf16_t* __restrict__ A, const bf16_t* __restrict__ Bt,
    const float* __restrict__ bias, const float2* __restrict__ lut,
    bf16_t* __restrict__ C, bf16_t* __restrict__ Kimg, f16_t* __restrict__ Vimg)
{
  __shared__ bf16_t As[2][128 * 64];
  __shared__ bf16_t Bs[2][64 * 64];
  const int tid  = threadIdx.x;
  const int w    = tid >> 6;
  const int lane = tid & 63;
  const int m    = lane & 15;
  const int quad = lane >> 4;
  const int wm   = w >> 1, wn = w & 1;

  // XCD-chunked bijective remap (grid 24x32 = 768 = 96/XCD)
  const int lin = blockIdx.y * 24 + blockIdx.x;
  const int swz = (lin & 7) * 96 + (lin >> 3);
  const int bx  = swz % 24;
  const int by  = swz / 24;
  const size_t bm = (size_t)by * 128;
  const size_t bn = (size_t)bx * 64;

  const int srow = w * 8 + (lane >> 3);
  const int scol = (lane & 7) * 8;
  const bf16_t* Ag = A  + (bm + srow) * HID + scol;
  const bf16_t* Bg = Bt + (bn + srow) * HID + scol;

  f32x4 acc[4][2];
#pragma unroll
  for (int i = 0; i < 4; ++i)
#pragma unroll
    for (int j = 0; j < 2; ++j) acc[i][j] = (f32x4){0.f, 0.f, 0.f, 0.f};

  // prologue stage k0=0 into buf 0
#pragma unroll
  for (int i = 0; i < 4; ++i)
    gl_lds16(Ag + (size_t)(i * 32) * HID, &As[0][(w * 8 + i * 32) * 64]);
#pragma unroll
  for (int i = 0; i < 2; ++i)
    gl_lds16(Bg + (size_t)(i * 32) * HID, &Bs[0][(w * 8 + i * 32) * 64]);

  int p = 0;
  for (int k0 = 0; k0 < HID; k0 += 64) {
    __syncthreads();                       // drains buf[p]'s DMA (issued last iter)
    if (k0 + 64 < HID) {                   // prefetch next into buf[p^1]
#pragma unroll
      for (int i = 0; i < 4; ++i)
        gl_lds16(Ag + (size_t)(i * 32) * HID + k0 + 64, &As[p^1][(w * 8 + i * 32) * 64]);
#pragma unroll
      for (int i = 0; i < 2; ++i)
        gl_lds16(Bg + (size_t)(i * 32) * HID + k0 + 64, &Bs[p^1][(w * 8 + i * 32) * 64]);
    }
#pragma unroll
    for (int ks = 0; ks < 2; ++ks) {
      bf16x8 af[4], bfr[2];
#pragma unroll
      for (int mt = 0; mt < 4; ++mt)
        af[mt] = *(const bf16x8*)&As[p][(wm * 64 + mt * 16 + m) * 64 + ks * 32 + quad * 8];
#pragma unroll
      for (int nt = 0; nt < 2; ++nt)
        bfr[nt] = *(const bf16x8*)&Bs[p][(wn * 32 + nt * 16 + m) * 64 + ks * 32 + quad * 8];
#pragma unroll
      for (int mt = 0; mt < 4; ++mt)
#pragma unroll
        for (int nt = 0; nt < 2; ++nt)
          acc[mt][nt] = __builtin_amdgcn_mfma_f32_16x16x32_bf16(bfr[nt], af[mt], acc[mt][nt], 0, 0, 0);
    }
    p ^= 1;
  }

  const int b   = by >> 4;           // batch
  const int rt  = by & 15;           // 128-row tile within batch

  if (bx < 16) {
    // ---- Q epilogue: bias, write QKVb (bf16) ----
#pragma unroll
    for (int mt = 0; mt < 4; ++mt) {
      const size_t row = bm + wm * 64 + mt * 16 + m;
#pragma unroll
      for (int nt = 0; nt < 2; ++nt) {
        const size_t col = bn + wn * 32 + nt * 16 + quad * 4;
        float4 bb = *(const float4*)&bias[col];
        bf16x4 o;
        o[0] = (bf16_t)(acc[mt][nt][0] + bb.x);
        o[1] = (bf16_t)(acc[mt][nt][1] + bb.y);
        o[2] = (bf16_t)(acc[mt][nt][2] + bb.z);
        o[3] = (bf16_t)(acc[mt][nt][3] + bb.w);
        *(bf16x4*)&C[row * NQKV + col] = o;
      }
    }
  } else if (bx < 20) {
    // ---- K epilogue: bias + RoPE on f32 acc, write swizzled Kimg ----
    const int kvh = bx - 16;
    const size_t img0 = ((size_t)(b * NKV_ + kvh) * 32 + rt * 2) * 4096;
#pragma unroll
    for (int mt = 0; mt < 4; ++mt) {
      const int row128 = wm * 64 + mt * 16 + m;      // 0..127
      const int srw    = rt * 128 + row128;          // seq pos 0..2047
      const int key    = row128 & 63;
      const size_t img = img0 + (size_t)(row128 >> 6) * 4096;
#pragma unroll
      for (int nt = 0; nt < 2; ++nt) {
        const int d0 = wn * 32 + nt * 16 + quad * 4; // 0..60 step 4
        const float4 bb = *(const float4*)&bias[1024 + kvh * DH_ + d0];
        const float v0 = acc[mt][nt][0] + bb.x;
        const float v1 = acc[mt][nt][1] + bb.y;
        const float v2 = acc[mt][nt][2] + bb.z;
        const float v3 = acc[mt][nt][3] + bb.w;
        const float2* lp = lut + srw * 32 + (d0 & 31);
        const float2 l0 = lp[0], l1 = lp[1], l2 = lp[2], l3 = lp[3];
        bf16x4 o;
        o[0] = (bf16_t)(v0 * l0.x - v1 * l0.y);
        o[1] = (bf16_t)(v1 * l1.x + v0 * l1.y);
        o[2] = (bf16_t)(v2 * l2.x - v3 * l2.y);
        o[3] = (bf16_t)(v3 * l3.x + v2 * l3.y);
        const int slot = (d0 >> 3) ^ (key & 7);
        *(bf16x4*)&Kimg[img + key * 64 + slot * 8 + (d0 & 7)] = o;
      }
    }
  } else {
    // ---- V epilogue: bias, LDS transpose (reuse As), write 32-key Vimg ----
    // Vimg32: per (b,kvh,kt32): [d in 64][slot*4+(key&3)], slot=(key32>>2)^(d&7)
    const int kvh = bx - 20;
    f16_t* Lv = (f16_t*)&As[0][0];                    // [128][68] f16 = 17 KB
    __syncthreads();                                  // all waves done with As/Bs
#pragma unroll
    for (int mt = 0; mt < 4; ++mt) {
      const int row128 = wm * 64 + mt * 16 + m;
#pragma unroll
      for (int nt = 0; nt < 2; ++nt) {
        const int d0 = wn * 32 + nt * 16 + quad * 4;
        const float4 bb = *(const float4*)&bias[1280 + kvh * DH_ + d0];
        f16x4 o;
        o[0] = (f16_t)(acc[mt][nt][0] + bb.x);
        o[1] = (f16_t)(acc[mt][nt][1] + bb.y);
        o[2] = (f16_t)(acc[mt][nt][2] + bb.z);
        o[3] = (f16_t)(acc[mt][nt][3] + bb.w);
        *(f16x4*)&Lv[row128 * 68 + d0] = o;
      }
    }
    __syncthreads();
    const size_t imgb = ((size_t)(b * NKV_ + kvh) * 64 + rt * 4) * 2048;
    const int d  = tid & 63;
    const int qg = tid >> 6;                          // 0..3
#pragma unroll
    for (int i = 0; i < 8; ++i) {
      const int ki = i >> 1;                          // 32-key image 0..3
      const int g8 = qg * 2 + (i & 1);                // key group-of-4: 0..7
      f16x4 o;
#pragma unroll
      for (int j = 0; j < 4; ++j)
        o[j] = Lv[(ki * 32 + g8 * 4 + j) * 68 + d];
      const int slot = g8 ^ (d & 7);
      *(f16x4*)&Vimg[imgb + (size_t)ki * 2048 + d * 32 + slot * 4] = o;
    }
  }
}

// ---------------------------------------------------------------------------
// gemm64_f32o (R2-proven) + XCD swizzle.
// ---------------------------------------------------------------------------
__global__ __launch_bounds__(256, 3) void gemm64_f32o(
    const bf16_t* __restrict__ A, const bf16_t* __restrict__ Bt,
    const float* __restrict__ bias, float* __restrict__ C, int N)
{
  __shared__ bf16_t As[2][128 * 64];
  __shared__ bf16_t Bs[2][64 * 64];
  const int tid  = threadIdx.x;
  const int w    = tid >> 6;
  const int lane = tid & 63;
  const int m    = lane & 15;
  const int quad = lane >> 4;
  const int wm   = w >> 1, wn = w & 1;

  // XCD-chunked bijective remap (grid 16x32 = 512 = 64/XCD)
  const int lin = blockIdx.y * 16 + blockIdx.x;
  const int swz = (lin & 7) * 64 + (lin >> 3);
  const int bx  = swz & 15;
  const int by  = swz >> 4;
  const size_t bm = (size_t)by * 128;
  const size_t bn = (size_t)bx * 64;

  const int srow = w * 8 + (lane >> 3);
  const int scol = (lane & 7) * 8;
  const bf16_t* Ag = A  + (bm + srow) * HID + scol;
  const bf16_t* Bg = Bt + (bn + srow) * HID + scol;

  f32x4 acc[4][2];
#pragma unroll
  for (int i = 0; i < 4; ++i)
#pragma unroll
    for (int j = 0; j < 2; ++j) acc[i][j] = (f32x4){0.f, 0.f, 0.f, 0.f};

#pragma unroll
  for (int i = 0; i < 4; ++i)
    gl_lds16(Ag + (size_t)(i * 32) * HID, &As[0][(w * 8 + i * 32) * 64]);
#pragma unroll
  for (int i = 0; i < 2; ++i)
    gl_lds16(Bg + (size_t)(i * 32) * HID, &Bs[0][(w * 8 + i * 32) * 64]);

  int p = 0;
  for (int k0 = 0; k0 < HID; k0 += 64) {
    __syncthreads();
    if (k0 + 64 < HID) {
#pragma unroll
      for (int i = 0; i < 4; ++i)
        gl_lds16(Ag + (size_t)(i * 32) * HID + k0 + 64, &As[p^1][(w * 8 + i * 32) * 64]);
#pragma unroll
      for (int i = 0; i < 2; ++i)
        gl_lds16(Bg + (size_t)(i * 32) * HID + k0 + 64, &Bs[p^1][(w * 8 + i * 32) * 64]);
    }
#pragma unroll
    for (int ks = 0; ks < 2; ++ks) {
      bf16x8 af[4], bfr[2];
#pragma unroll
      for (int mt = 0; mt < 4; ++mt)
        af[mt] = *(const bf16x8*)&As[p][(wm * 64 + mt * 16 + m) * 64 + ks * 32 + quad * 8];
#pragma unroll
      for (int nt = 0; nt < 2; ++nt)
        bfr[nt] = *(const bf16x8*)&Bs[p][(wn * 32 + nt * 16 + m) * 64 + ks * 32 + quad * 8];
#pragma unroll
      for (int mt = 0; mt < 4; ++mt)
#pragma unroll
        for (int nt = 0; nt < 2; ++nt)
          acc[mt][nt] = __builtin_amdgcn_mfma_f32_16x16x32_bf16(bfr[nt], af[mt], acc[mt][nt], 0, 0, 0);
    }
    p ^= 1;
  }
#pragma unroll
  for (int mt = 0; mt < 4; ++mt) {
    const size_t row = bm + wm * 64 + mt * 16 + m;
#pragma unroll
    for (int nt = 0; nt < 2; ++nt) {
      const size_t col = bn + wn * 32 + nt * 16 + quad * 4;
      float4 bb = *(const float4*)&bias[col];
      float4 o;
      o.x = acc[mt][nt][0] + bb.x; o.y = acc[mt][nt][1] + bb.y;
      o.z = acc[mt][nt][2] + bb.z; o.w = acc[mt][nt][3] + bb.w;
      *(float4*)&C[row * N + col] = o;
    }
  }
}

// ---------------------------------------------------------------------------
// attn_v12: v8 schedule at KVBLK=32 with 1024-thread blocks (8 waves/SIMD).
// 4 wave-groups interleave the pair's uniform 65-element 32-key sequence
// (e = 4t+g, 17 iters).  LDS = 4 groups x dbuf x (4KB K + 4KB V) = 64 KB
// -> 2 blocks/CU.  4-partial in-block merge in freed LDS.
// ---------------------------------------------------------------------------
#define PROC_T32(AQ, OACC, LP, Q0W)                                           \
  do {                                                                        \
    const bf16_t* kp = Ksb + (g * 2 + p) * 2048;                              \
    const f16_t*  vp = Vsb + (g * 2 + p) * 2048;                              \
    f32x4 sc[2];                                                              \
    sc[0] = (f32x4){0.f,0.f,0.f,0.f}; sc[1] = (f32x4){0.f,0.f,0.f,0.f};       \
    _Pragma("unroll") for (int cb = 0; cb < 2; ++cb) {                        \
      const bf16x8 bk0 = *(const bf16x8*)(kp + (cb*16 + m) * 64 + x0s * 8);   \
      const bf16x8 bk1 = *(const bf16x8*)(kp + (cb*16 + m) * 64 + x1s * 8);   \
      sc[cb] = __builtin_amdgcn_mfma_f32_16x16x32_bf16(bk0, AQ[0], sc[cb], 0, 0, 0); \
      sc[cb] = __builtin_amdgcn_mfma_f32_16x16x32_bf16(bk1, AQ[1], sc[cb], 0, 0, 0); \
    }                                                                         \
    f16x4 bp[2];                                                              \
    {                                                                         \
      const bool needm = (kbase + 31 > (Q0W)) || (mb != ~0ull);               \
      if (needm) {                                                            \
        const int qv = (Q0W) + m;                                             \
        _Pragma("unroll") for (int cb = 0; cb < 2; ++cb)                      \
          _Pragma("unroll") for (int r = 0; r < 4; ++r) {                     \
            const int idx = cb*16 + quad*4 + r;                               \
            const bool ok = (kbase + idx <= qv) && ((mb >> idx) & 1);         \
            sc[cb][r] = ok ? sc[cb][r] : -1e38f;                              \
          }                                                                   \
      }                                                                       \
      float sum = 0.f;                                                        \
      _Pragma("unroll") for (int cb = 0; cb < 2; ++cb) {                      \
        f16x4 pp;                                                             \
        _Pragma("unroll") for (int r = 0; r < 4; ++r) {                       \
          const float pv = __builtin_amdgcn_exp2f(sc[cb][r]);                 \
          sum += pv;                                                          \
          pp[r] = (f16_t)pv;                                                  \
        }                                                                     \
        bp[cb] = pp;                                                          \
      }                                                                       \
      LP += sum;                                                              \
    }                                                                         \
    _Pragma("unroll") for (int cb = 0; cb < 2; ++cb) {                        \
      const int slot = (cb * 4 + quad) ^ (m & 7);                             \
      _Pragma("unroll") for (int dblk = 0; dblk < 4; ++dblk) {                \
        const f16x4 av = *(const f16x4*)(vp + (dblk*16 + m) * 32 + slot * 4); \
        OACC[dblk] = __builtin_amdgcn_mfma_f32_16x16x16f16(av, bp[cb], OACC[dblk], 0, 0, 0); \
      }                                                                       \
    }                                                                         \
  } while (0)

__global__ __launch_bounds__(1024, 8) void attn_v12(
    const bf16_t* __restrict__ QKVb, const float2* __restrict__ lut,
    const bf16_t* __restrict__ Kt2, const f16_t* __restrict__ Vt2,
    const int* __restrict__ amask, bf16_t* __restrict__ Ab)
{
  __shared__ __align__(16) uint8_t SMEM[65536];
  bf16_t* Ksb = (bf16_t*)SMEM;              // [4 groups][2 bufs][2048]
  f16_t*  Vsb = (f16_t*)(SMEM + 32768);     // [4 groups][2 bufs][2048]

  const int tid  = threadIdx.x;
  const int w    = tid >> 6;         // 0..15
  const int g    = w >> 2;           // wave-group 0..3 (sequence stride 4)
  const int wl   = w & 3;            // head-in-group
  const int lane = tid & 63;
  const int m    = lane & 15;
  const int quad = lane >> 4;
  const int kvh  = blockIdx.y;
  const int b    = blockIdx.z;
  const int h    = kvh * 4 + wl;
  const int x    = blockIdx.x;       // 0..63
  const int q0wA = x * 16;
  const int q0wB = (127 - x) * 16;
  const int nA   = (x >> 1) + 1;     // 32-key tiles for A; T = nA+nB = 65 all x

  // ---- Q fragments (both tiles) with fused RoPE + scale ----
  bf16x8 aqA[2], aqB[2];
#pragma unroll
  for (int tt = 0; tt < 2; ++tt) {
    const int q0w_t = tt ? q0wB : q0wA;
    const int spos = q0w_t + m;
    const bf16_t* qsrc = QKVb + (size_t)(b * S_ + spos) * NQKV + h * DH_;
    float2 l8[8];
#pragma unroll
    for (int j = 0; j < 8; ++j) l8[j] = lut[spos * 32 + quad * 8 + j];
#pragma unroll
    for (int kc = 0; kc < 2; ++kc) {
      bf16x8 xv = *(const bf16x8*)(qsrc + kc * 32 + quad * 8);
      bf16x8 y;
#pragma unroll
      for (int i = 0; i < 4; ++i) {
        const float x0 = (float)xv[2*i], x1 = (float)xv[2*i+1];
        y[2*i]   = (bf16_t)((x0 * l8[2*i].x   - x1 * l8[2*i].y)   * QSCALE);
        y[2*i+1] = (bf16_t)((x1 * l8[2*i+1].x + x0 * l8[2*i+1].y) * QSCALE);
      }
      if (tt) aqB[kc] = y; else aqA[kc] = y;
    }
  }

  f32x4 oaccA[4], oaccB[4];
#pragma unroll
  for (int d = 0; d < 4; ++d) {
    oaccA[d] = (f32x4){0.f,0.f,0.f,0.f};
    oaccB[d] = (f32x4){0.f,0.f,0.f,0.f};
  }
  float lpA = 0.f, lpB = 0.f;

  const size_t imgbase = (size_t)(b * NKV_ + kvh) * 131072;   // 64 x 2048
  const bf16_t* Kg = Kt2 + imgbase;   // 32-key K chunk c: contiguous at c*2048
  const f16_t*  Vg = Vt2 + imgbase;   // 32-key V image at c*2048
  const int x0s = quad ^ (m & 7);
  const int x1s = (4 + quad) ^ (m & 7);
  const int* amp = amask + b * S_;

  // prologue: group g stages its first element (e = g) into buf 0
  int mcur;
  {
    const int e0  = g;
    const int kt0 = (e0 >= nA) ? e0 - nA : e0;
    gl_lds16(Kg + (size_t)kt0 * 2048 + wl * 512 + lane * 8, Ksb + (g*2) * 2048 + wl * 512);
    gl_lds16(Vg + (size_t)kt0 * 2048 + wl * 512 + lane * 8, Vsb + (g*2) * 2048 + wl * 512);
    mcur = amp[kt0 * 32 + (lane & 31)];
  }

  int p = 0;
  for (int t = 0; t < 17; ++t) {
    const int e = 4 * t + g;
    __syncthreads();                 // drains buf[*][p]'s DMA (issued last iter)
    const int e4 = e + 4;
    const bool more = (e4 < 65);
    int ktn = 0;
    if (more) {
      ktn = (e4 >= nA) ? e4 - nA : e4;
      gl_lds16(Kg + (size_t)ktn * 2048 + wl * 512 + lane * 8, Ksb + (g*2 + (p^1)) * 2048 + wl * 512);
      gl_lds16(Vg + (size_t)ktn * 2048 + wl * 512 + lane * 8, Vsb + (g*2 + (p^1)) * 2048 + wl * 512);
    }
    const int mnext = more ? amp[ktn * 32 + (lane & 31)] : 0;
    if (e < 65) {
      const uint64_t mb = __ballot(mcur != 0);
      const bool isB = (e >= nA);
      const int kt = isB ? e - nA : e;
      const int kbase = kt * 32;
      if (isB) PROC_T32(aqB, oaccB, lpB, q0wB);
      else     PROC_T32(aqA, oaccA, lpA, q0wA);
    }
    mcur = mnext;
    p ^= 1;
  }

  // ---- epilogue: 4-partial merge via LDS scratch (pure adds), store ----
  float lA = lpA; lA += __shfl_xor(lA, 16); lA += __shfl_xor(lA, 32);
  float lB = lpB; lB += __shfl_xor(lB, 16); lB += __shfl_xor(lB, 32);

  float* scr = (float*)SMEM;          // 3 regions x 4416 floats = 53 KB
  const int sb_ = m * 68 + quad * 4;  // within 1104-float head region

  __syncthreads();                    // all tile compute done
  if (g >= 1) {                       // groups 1..3 write A partials
    float* r = scr + (g - 1) * 4416 + wl * 1104;
#pragma unroll
    for (int dblk = 0; dblk < 4; ++dblk)
      *(f32x4*)&r[sb_ + dblk * 16] = oaccA[dblk];
    if (quad == 0) r[1088 + m] = lA;
  }
  __syncthreads();
  if (g == 0) {                       // finalize tile A
    float l = lA;
#pragma unroll
    for (int rg = 0; rg < 3; ++rg) l += scr[rg * 4416 + wl * 1104 + 1088 + m];
    const float inv = 1.0f / l;
    const size_t row = (size_t)(b * S_ + q0wA + m);
#pragma unroll
    for (int dblk = 0; dblk < 4; ++dblk) {
      f32x4 s = oaccA[dblk];
#pragma unroll
      for (int rg = 0; rg < 3; ++rg)
        s += *(const f32x4*)&scr[rg * 4416 + wl * 1104 + sb_ + dblk * 16];
      bf16x4 o;
      o[0] = (bf16_t)(s[0] * inv);
      o[1] = (bf16_t)(s[1] * inv);
      o[2] = (bf16_t)(s[2] * inv);
      o[3] = (bf16_t)(s[3] * inv);
      *(bf16x4*)&Ab[row * HID + h * DH_ + dblk * 16 + quad * 4] = o;
    }
  }
  __syncthreads();
  if (g >= 1) {                       // groups 1..3 write B partials
    float* r = scr + (g - 1) * 4416 + wl * 1104;
#pragma unroll
    for (int dblk = 0; dblk < 4; ++dblk)
      *(f32x4*)&r[sb_ + dblk * 16] = oaccB[dblk];
    if (quad == 0) r[1088 + m] = lB;
  }
  __syncthreads();
  if (g == 0) {                       // finalize tile B
    float l = lB;
#pragma unroll
    for (int rg = 0; rg < 3; ++rg) l += scr[rg * 4416 + wl * 1104 + 1088 + m];
    const float inv = 1.0f / l;
    const size_t row = (size_t)(b * S_ + q0wB + m);
#pragma unroll
    for (int dblk = 0; dblk < 4; ++dblk) {
      f32x4 s = oaccB[dblk];
#pragma unroll
      for (int rg = 0; rg < 3; ++rg)
        s += *(const f32x4*)&scr[rg * 4416 + wl * 1104 + sb_ + dblk * 16];
      bf16x4 o;
      o[0] = (bf16_t)(s[0] * inv);
      o[1] = (bf16_t)(s[1] * inv);
      o[2] = (bf16_t)(s[2] * inv);
      o[3] = (bf16_t)(s[3] * inv);
      *(bf16x4*)&Ab[row * HID + h * DH_ + dblk * 16 + quad * 4] = o;
    }
  }
}

// ---------------------------------------------------------------------------
extern "C" void kernel_launch(void* const* d_in, const int* in_sizes, int n_in,
                              void* d_out, int out_size, void* d_ws, size_t ws_size,
                              hipStream_t stream)
{
  const float* hs    = (const float*)d_in[0];
  const int*   amask = (const int*)  d_in[1];
  const float* Wq    = (const float*)d_in[2];
  const float* bq    = (const float*)d_in[3];
  const float* Wk    = (const float*)d_in[4];
  const float* bk    = (const float*)d_in[5];
  const float* Wv    = (const float*)d_in[6];
  const float* bv    = (const float*)d_in[7];
  const float* Wo    = (const float*)d_in[8];
  const float* bo    = (const float*)d_in[9];
  float* out = (float*)d_out;

  // workspace layout (~31 MB)
  bf16_t* QKVb = (bf16_t*)d_ws;                            // 12.6 MB (live through attn)
  bf16_t* hsb  = QKVb + (size_t)ROWS * NQKV;               // 8 MB (Ab aliases after QKV GEMM)
  bf16_t* Wt   = hsb + (size_t)ROWS * HID;                 // 3 MB
  bf16_t* Wot  = Wt + (size_t)NQKV * HID;                  // 2 MB
  float*  ball = (float*)(Wot + (size_t)HID * HID);        // 6 KB
  bf16_t* Kimg = (bf16_t*)(ball + NQKV);                   // 2 MB
  f16_t*  Vimg = (f16_t*)(Kimg + (size_t)B_*NKV_*32*4096); // 2 MB
  float2* lut  = (float2*)(Vimg + (size_t)B_*NKV_*32*4096);// 0.5 MB
  bf16_t* Ab   = hsb;                                      // alias (hsb dead after QKV GEMM)

  // fused prep: cast + weight transpose + biases + RoPE LUT
  prep_all<<<4870, 256, 0, stream>>>(hs, Wq, Wk, Wv, Wo, bq, bk, bv,
                                     hsb, Wt, Wot, ball, lut);

  // QKV projection + fused K/V image build (RoPE'd K, 32-key V images)
  gemm_qkv<<<dim3(NQKV/64, ROWS/128), 256, 0, stream>>>(hsb, Wt, ball, lut,
                                                        QKVb, Kimg, Vimg);

  // attention (paired q-tiles, KVBLK=32, 1024-thr blocks = 8 waves/SIMD)
  attn_v12<<<dim3(64, NKV_, B_), 1024, 0, stream>>>(QKVb, lut, Kimg, Vimg, amask, Ab);

  // output projection (512 blocks = 2/CU, dbuf, XCD-chunked swizzle)
  gemm64_f32o<<<dim3(HID/64, ROWS/128), 256, 0, stream>>>(Ab, Wot, bo, out, HID);
}

// Round 13
// 172.998 us; speedup vs baseline: 2.2576x; 2.2576x over previous
//
#include <hip/hip_runtime.h>
#include <cstddef>
#include <cstdint>

#define B_   2
#define S_   2048
#define HID  1024
#define NH_  16
#define NKV_ 4
#define DH_  64
#define ROWS (B_ * S_)   // 4096
#define NQKV 1536        // 1024 Q + 256 K + 256 V
#define QSCALE 0.18033688011112042f   // 0.125 * log2(e)  (exp2-domain softmax)

typedef __bf16 bf16_t;
typedef _Float16 f16_t;
typedef bf16_t bf16x8 __attribute__((ext_vector_type(8)));
typedef bf16_t bf16x4 __attribute__((ext_vector_type(4)));
typedef f16_t  f16x8  __attribute__((ext_vector_type(8)));
typedef f16_t  f16x4  __attribute__((ext_vector_type(4)));
typedef float  f32x4  __attribute__((ext_vector_type(4)));

typedef __attribute__((address_space(1))) const uint32_t gu32_t;
typedef __attribute__((address_space(3))) uint32_t lu32_t;

__device__ __forceinline__ void gl_lds16(const void* g, void* l) {
  __builtin_amdgcn_global_load_lds((gu32_t*)g, (lu32_t*)l, 16, 0, 0);
}

// ---------------------------------------------------------------------------
// prep_all (proven): fused cast + weight transpose + bias concat + RoPE LUT.
// ---------------------------------------------------------------------------
__global__ void prep_all(const float* __restrict__ hs,
                         const float* __restrict__ Wq, const float* __restrict__ Wk,
                         const float* __restrict__ Wv, const float* __restrict__ Wo,
                         const float* __restrict__ bq, const float* __restrict__ bk,
                         const float* __restrict__ bv,
                         bf16_t* __restrict__ hsb,
                         bf16_t* __restrict__ Wt, bf16_t* __restrict__ Wot,
                         float* __restrict__ ball, float2* __restrict__ lut)
{
  const int bid = blockIdx.x;
  if (bid < 2048) {                        // ---- cast hs -> bf16 ----
    const int i = (bid * 256 + threadIdx.x) * 8;
    float4 a = *(const float4*)(hs + i);
    float4 b = *(const float4*)(hs + i + 4);
    bf16x8 o;
    o[0]=(bf16_t)a.x; o[1]=(bf16_t)a.y; o[2]=(bf16_t)a.z; o[3]=(bf16_t)a.w;
    o[4]=(bf16_t)b.x; o[5]=(bf16_t)b.y; o[6]=(bf16_t)b.z; o[7]=(bf16_t)b.w;
    *(bf16x8*)(hsb + i) = o;
    return;
  }
  if (bid >= 4614) {                       // ---- RoPE LUT ----
    const int idx = (bid - 4614) * 256 + threadIdx.x;   // [0,65536)
    const int s = idx >> 5, j = idx & 31;
    const float L = 0.51905126482615037f;  // log2(1e5)/32
    const float ang = (float)s * exp2f(-L * (float)j);
    lut[idx] = make_float2(cosf(ang), sinf(ang));
    return;
  }
  if (bid >= 4608) {                       // ---- biases ----
    int i = (bid - 4608) * 256 + threadIdx.x;
    if (i < NQKV) ball[i] = (i < 1024) ? bq[i] : ((i < 1280) ? bk[i-1024] : bv[i-1280]);
    return;
  }
  const int wb = bid - 2048;               // ---- weight transpose ----
  const float* src; bf16_t* dst; int N, n0, k0;
  if (wb < 1024)      { src = Wq; dst = Wt;            N = 1024; int t = wb;      n0=(t&31)*32; k0=(t>>5)*32; }
  else if (wb < 1280) { src = Wk; dst = Wt + 1024*HID; N = 256;  int t = wb-1024; n0=(t&7)*32;  k0=(t>>3)*32; }
  else if (wb < 1536) { src = Wv; dst = Wt + 1280*HID; N = 256;  int t = wb-1280; n0=(t&7)*32;  k0=(t>>3)*32; }
  else                { src = Wo; dst = Wot;           N = 1024; int t = wb-1536; n0=(t&31)*32; k0=(t>>5)*32; }
  __shared__ bf16_t T[32][33];
  const int tx = threadIdx.x & 31, ty = threadIdx.x >> 5;
#pragma unroll
  for (int i = 0; i < 4; ++i)
    T[ty + i*8][tx] = (bf16_t)src[(size_t)(k0 + ty + i*8) * N + n0 + tx];
  __syncthreads();
#pragma unroll
  for (int i = 0; i < 4; ++i)
    dst[(size_t)(n0 + ty + i*8) * HID + k0 + tx] = T[tx][ty + i*8];
}

// ---------------------------------------------------------------------------
// gemm_qkv (R7-proven): 128x64 GEMM + XCD swizzle + fused prep_kv epilogue.
// ---------------------------------------------------------------------------
__global__ __launch_bounds__(256, 3) void gemm_qkv(
    const bf16_t* __restrict__ A, const bf16_t* __restrict__ Bt,
    const float* __restrict__ bias, const float2* __restrict__ lut,
    bf16_t* __restrict__ C, bf16_t* __restrict__ Kimg, f16_t* __restrict__ Vimg)
{
  __shared__ bf16_t As[2][128 * 64];
  __shared__ bf16_t Bs[2][64 * 64];
  const int tid  = threadIdx.x;
  const int w    = tid >> 6;
  const int lane = tid & 63;
  const int m    = lane & 15;
  const int quad = lane >> 4;
  const int wm   = w >> 1, wn = w & 1;

  // XCD-chunked bijective remap (grid 24x32 = 768 = 96/XCD)
  const int lin = blockIdx.y * 24 + blockIdx.x;
  const int swz = (lin & 7) * 96 + (lin >> 3);
  const int bx  = swz % 24;
  const int by  = swz / 24;
  const size_t bm = (size_t)by * 128;
  const size_t bn = (size_t)bx * 64;

  const int srow = w * 8 + (lane >> 3);
  const int scol = (lane & 7) * 8;
  const bf16_t* Ag = A  + (bm + srow) * HID + scol;
  const bf16_t* Bg = Bt + (bn + srow) * HID + scol;

  f32x4 acc[4][2];
#pragma unroll
  for (int i = 0; i < 4; ++i)
#pragma unroll
    for (int j = 0; j < 2; ++j) acc[i][j] = (f32x4){0.f, 0.f, 0.f, 0.f};

  // prologue stage k0=0 into buf 0
#pragma unroll
  for (int i = 0; i < 4; ++i)
    gl_lds16(Ag + (size_t)(i * 32) * HID, &As[0][(w * 8 + i * 32) * 64]);
#pragma unroll
  for (int i = 0; i < 2; ++i)
    gl_lds16(Bg + (size_t)(i * 32) * HID, &Bs[0][(w * 8 + i * 32) * 64]);

  int p = 0;
  for (int k0 = 0; k0 < HID; k0 += 64) {
    __syncthreads();                       // drains buf[p]'s DMA (issued last iter)
    if (k0 + 64 < HID) {                   // prefetch next into buf[p^1]
#pragma unroll
      for (int i = 0; i < 4; ++i)
        gl_lds16(Ag + (size_t)(i * 32) * HID + k0 + 64, &As[p^1][(w * 8 + i * 32) * 64]);
#pragma unroll
      for (int i = 0; i < 2; ++i)
        gl_lds16(Bg + (size_t)(i * 32) * HID + k0 + 64, &Bs[p^1][(w * 8 + i * 32) * 64]);
    }
#pragma unroll
    for (int ks = 0; ks < 2; ++ks) {
      bf16x8 af[4], bfr[2];
#pragma unroll
      for (int mt = 0; mt < 4; ++mt)
        af[mt] = *(const bf16x8*)&As[p][(wm * 64 + mt * 16 + m) * 64 + ks * 32 + quad * 8];
#pragma unroll
      for (int nt = 0; nt < 2; ++nt)
        bfr[nt] = *(const bf16x8*)&Bs[p][(wn * 32 + nt * 16 + m) * 64 + ks * 32 + quad * 8];
#pragma unroll
      for (int mt = 0; mt < 4; ++mt)
#pragma unroll
        for (int nt = 0; nt < 2; ++nt)
          acc[mt][nt] = __builtin_amdgcn_mfma_f32_16x16x32_bf16(bfr[nt], af[mt], acc[mt][nt], 0, 0, 0);
    }
    p ^= 1;
  }

  const int b   = by >> 4;           // batch
  const int rt  = by & 15;           // 128-row tile within batch

  if (bx < 16) {
    // ---- Q epilogue: bias, write QKVb (bf16) ----
#pragma unroll
    for (int mt = 0; mt < 4; ++mt) {
      const size_t row = bm + wm * 64 + mt * 16 + m;
#pragma unroll
      for (int nt = 0; nt < 2; ++nt) {
        const size_t col = bn + wn * 32 + nt * 16 + quad * 4;
        float4 bb = *(const float4*)&bias[col];
        bf16x4 o;
        o[0] = (bf16_t)(acc[mt][nt][0] + bb.x);
        o[1] = (bf16_t)(acc[mt][nt][1] + bb.y);
        o[2] = (bf16_t)(acc[mt][nt][2] + bb.z);
        o[3] = (bf16_t)(acc[mt][nt][3] + bb.w);
        *(bf16x4*)&C[row * NQKV + col] = o;
      }
    }
  } else if (bx < 20) {
    // ---- K epilogue: bias + RoPE on f32 acc, write swizzled Kimg ----
    const int kvh = bx - 16;
    const size_t img0 = ((size_t)(b * NKV_ + kvh) * 32 + rt * 2) * 4096;
#pragma unroll
    for (int mt = 0; mt < 4; ++mt) {
      const int row128 = wm * 64 + mt * 16 + m;      // 0..127
      const int srw    = rt * 128 + row128;          // seq pos 0..2047
      const int key    = row128 & 63;
      const size_t img = img0 + (size_t)(row128 >> 6) * 4096;
#pragma unroll
      for (int nt = 0; nt < 2; ++nt) {
        const int d0 = wn * 32 + nt * 16 + quad * 4; // 0..60 step 4
        const float4 bb = *(const float4*)&bias[1024 + kvh * DH_ + d0];
        const float v0 = acc[mt][nt][0] + bb.x;
        const float v1 = acc[mt][nt][1] + bb.y;
        const float v2 = acc[mt][nt][2] + bb.z;
        const float v3 = acc[mt][nt][3] + bb.w;
        const float2* lp = lut + srw * 32 + (d0 & 31);
        const float2 l0 = lp[0], l1 = lp[1], l2 = lp[2], l3 = lp[3];
        bf16x4 o;
        o[0] = (bf16_t)(v0 * l0.x - v1 * l0.y);
        o[1] = (bf16_t)(v1 * l1.x + v0 * l1.y);
        o[2] = (bf16_t)(v2 * l2.x - v3 * l2.y);
        o[3] = (bf16_t)(v3 * l3.x + v2 * l3.y);
        const int slot = (d0 >> 3) ^ (key & 7);
        *(bf16x4*)&Kimg[img + key * 64 + slot * 8 + (d0 & 7)] = o;
      }
    }
  } else {
    // ---- V epilogue: bias, LDS transpose (reuse As), write swizzled Vimg ----
    const int kvh = bx - 20;
    f16_t* Lv = (f16_t*)&As[0][0];                    // [128][68] f16 = 17 KB
    __syncthreads();                                  // all waves done with As/Bs
#pragma unroll
    for (int mt = 0; mt < 4; ++mt) {
      const int row128 = wm * 64 + mt * 16 + m;
#pragma unroll
      for (int nt = 0; nt < 2; ++nt) {
        const int d0 = wn * 32 + nt * 16 + quad * 4;
        const float4 bb = *(const float4*)&bias[1280 + kvh * DH_ + d0];
        f16x4 o;
        o[0] = (f16_t)(acc[mt][nt][0] + bb.x);
        o[1] = (f16_t)(acc[mt][nt][1] + bb.y);
        o[2] = (f16_t)(acc[mt][nt][2] + bb.z);
        o[3] = (f16_t)(acc[mt][nt][3] + bb.w);
        *(f16x4*)&Lv[row128 * 68 + d0] = o;
      }
    }
    __syncthreads();
    const size_t img0 = ((size_t)(b * NKV_ + kvh) * 32 + rt * 2) * 4096;
    const int d  = tid & 63;
    const int qg = tid >> 6;                          // 0..3
#pragma unroll
    for (int i = 0; i < 8; ++i) {
      const int ki = i >> 2;                          // image 0/1 (keys 0-63 / 64-127)
      const int g4 = qg * 4 + (i & 3);                // key group 0..15
      f16x4 o;
#pragma unroll
      for (int j = 0; j < 4; ++j)
        o[j] = Lv[(ki * 64 + g4 * 4 + j) * 68 + d];
      const int slot = g4 ^ (d & 15);
      *(f16x4*)&Vimg[img0 + (size_t)ki * 4096 + d * 64 + slot * 4] = o;
    }
  }
}

// ---------------------------------------------------------------------------
// gemm64_f32o (R2-proven) + XCD swizzle.
// ---------------------------------------------------------------------------
__global__ __launch_bounds__(256, 3) void gemm64_f32o(
    const bf16_t* __restrict__ A, const bf16_t* __restrict__ Bt,
    const float* __restrict__ bias, float* __restrict__ C, int N)
{
  __shared__ bf16_t As[2][128 * 64];
  __shared__ bf16_t Bs[2][64 * 64];
  const int tid  = threadIdx.x;
  const int w    = tid >> 6;
  const int lane = tid & 63;
  const int m    = lane & 15;
  const int quad = lane >> 4;
  const int wm   = w >> 1, wn = w & 1;

  // XCD-chunked bijective remap (grid 16x32 = 512 = 64/XCD)
  const int lin = blockIdx.y * 16 + blockIdx.x;
  const int swz = (lin & 7) * 64 + (lin >> 3);
  const int bx  = swz & 15;
  const int by  = swz >> 4;
  const size_t bm = (size_t)by * 128;
  const size_t bn = (size_t)bx * 64;

  const int srow = w * 8 + (lane >> 3);
  const int scol = (lane & 7) * 8;
  const bf16_t* Ag = A  + (bm + srow) * HID + scol;
  const bf16_t* Bg = Bt + (bn + srow) * HID + scol;

  f32x4 acc[4][2];
#pragma unroll
  for (int i = 0; i < 4; ++i)
#pragma unroll
    for (int j = 0; j < 2; ++j) acc[i][j] = (f32x4){0.f, 0.f, 0.f, 0.f};

#pragma unroll
  for (int i = 0; i < 4; ++i)
    gl_lds16(Ag + (size_t)(i * 32) * HID, &As[0][(w * 8 + i * 32) * 64]);
#pragma unroll
  for (int i = 0; i < 2; ++i)
    gl_lds16(Bg + (size_t)(i * 32) * HID, &Bs[0][(w * 8 + i * 32) * 64]);

  int p = 0;
  for (int k0 = 0; k0 < HID; k0 += 64) {
    __syncthreads();
    if (k0 + 64 < HID) {
#pragma unroll
      for (int i = 0; i < 4; ++i)
        gl_lds16(Ag + (size_t)(i * 32) * HID + k0 + 64, &As[p^1][(w * 8 + i * 32) * 64]);
#pragma unroll
      for (int i = 0; i < 2; ++i)
        gl_lds16(Bg + (size_t)(i * 32) * HID + k0 + 64, &Bs[p^1][(w * 8 + i * 32) * 64]);
    }
#pragma unroll
    for (int ks = 0; ks < 2; ++ks) {
      bf16x8 af[4], bfr[2];
#pragma unroll
      for (int mt = 0; mt < 4; ++mt)
        af[mt] = *(const bf16x8*)&As[p][(wm * 64 + mt * 16 + m) * 64 + ks * 32 + quad * 8];
#pragma unroll
      for (int nt = 0; nt < 2; ++nt)
        bfr[nt] = *(const bf16x8*)&Bs[p][(wn * 32 + nt * 16 + m) * 64 + ks * 32 + quad * 8];
#pragma unroll
      for (int mt = 0; mt < 4; ++mt)
#pragma unroll
        for (int nt = 0; nt < 2; ++nt)
          acc[mt][nt] = __builtin_amdgcn_mfma_f32_16x16x32_bf16(bfr[nt], af[mt], acc[mt][nt], 0, 0, 0);
    }
    p ^= 1;
  }
#pragma unroll
  for (int mt = 0; mt < 4; ++mt) {
    const size_t row = bm + wm * 64 + mt * 16 + m;
#pragma unroll
    for (int nt = 0; nt < 2; ++nt) {
      const size_t col = bn + wn * 32 + nt * 16 + quad * 4;
      float4 bb = *(const float4*)&bias[col];
      float4 o;
      o.x = acc[mt][nt][0] + bb.x; o.y = acc[mt][nt][1] + bb.y;
      o.z = acc[mt][nt][2] + bb.z; o.w = acc[mt][nt][3] + bb.w;
      *(float4*)&C[row * N + col] = o;
    }
  }
}

// ---------------------------------------------------------------------------
// attn_v11 (R10-proven): v8 structure with raw v_exp_f32 softmax.
// ---------------------------------------------------------------------------
#define PROC_TILE(AQ, OACC, LP, Q0W)                                          \
  do {                                                                        \
    f32x4 sc[4];                                                              \
    _Pragma("unroll") for (int cb = 0; cb < 4; ++cb)                          \
      sc[cb] = (f32x4){0.f, 0.f, 0.f, 0.f};                                   \
    _Pragma("unroll") for (int cb = 0; cb < 4; ++cb) {                        \
      const bf16x8 bk0 = *(const bf16x8*)&Ks[g][p][(cb*16 + m) * 64 + x0s * 8]; \
      const bf16x8 bk1 = *(const bf16x8*)&Ks[g][p][(cb*16 + m) * 64 + x1s * 8]; \
      sc[cb] = __builtin_amdgcn_mfma_f32_16x16x32_bf16(bk0, AQ[0], sc[cb], 0, 0, 0); \
      sc[cb] = __builtin_amdgcn_mfma_f32_16x16x32_bf16(bk1, AQ[1], sc[cb], 0, 0, 0); \
    }                                                                         \
    f16x4 bp[4];                                                              \
    {                                                                         \
      const bool needm = (kbase + 63 > (Q0W)) || (mb != ~0ull);               \
      if (needm) {                                                            \
        const int qv = (Q0W) + m;                                             \
        _Pragma("unroll") for (int cb = 0; cb < 4; ++cb)                      \
          _Pragma("unroll") for (int r = 0; r < 4; ++r) {                     \
            const int idx = cb*16 + quad*4 + r;                               \
            const bool ok = (kbase + idx <= qv) && ((mb >> idx) & 1);         \
            sc[cb][r] = ok ? sc[cb][r] : -1e38f;                              \
          }                                                                   \
      }                                                                       \
      float sum = 0.f;                                                        \
      _Pragma("unroll") for (int cb = 0; cb < 4; ++cb) {                      \
        f16x4 pp;                                                             \
        _Pragma("unroll") for (int r = 0; r < 4; ++r) {                       \
          const float pv = __builtin_amdgcn_exp2f(sc[cb][r]);                 \
          sum += pv;                                                          \
          pp[r] = (f16_t)pv;                                                  \
        }                                                                     \
        bp[cb] = pp;                                                          \
      }                                                                       \
      LP += sum;                                                              \
    }                                                                         \
    _Pragma("unroll") for (int cb = 0; cb < 4; ++cb) {                        \
      f16x4 av[4];                                                            \
      _Pragma("unroll") for (int dblk = 0; dblk < 4; ++dblk) {                \
        const int slot = (cb * 4 + quad) ^ m;                                 \
        av[dblk] = *(const f16x4*)&Vs[g][p][(dblk*16 + m) * 64 + slot * 4];   \
      }                                                                       \
      _Pragma("unroll") for (int dblk = 0; dblk < 4; ++dblk)                  \
        OACC[dblk] = __builtin_amdgcn_mfma_f32_16x16x16f16(av[dblk], bp[cb], OACC[dblk], 0, 0, 0); \
    }                                                                         \
  } while (0)

__global__ __launch_bounds__(512, 4) void attn_v11(
    const bf16_t* __restrict__ QKVb, const float2* __restrict__ lut,
    const bf16_t* __restrict__ Kt2, const f16_t* __restrict__ Vt2,
    const int* __restrict__ amask, bf16_t* __restrict__ Ab)
{
  __shared__ __align__(16) bf16_t Ks[2][2][64 * 64];   // 32 KB (2 groups x dbuf)
  __shared__ __align__(16) f16_t  Vs[2][2][64 * 64];   // 32 KB

  const int tid  = threadIdx.x;
  const int w    = tid >> 6;         // 0..7
  const int g    = w >> 2;           // wave-group: even / odd sequence elements
  const int wl   = w & 3;            // head-in-group
  const int lane = tid & 63;
  const int m    = lane & 15;
  const int quad = lane >> 4;
  const int kvh  = blockIdx.y;
  const int b    = blockIdx.z;
  const int h    = kvh * 4 + wl;
  const int x    = blockIdx.x;       // 0..63
  const int q0wA = x * 16;
  const int q0wB = (127 - x) * 16;
  const int nA   = (x >> 2) + 1;
  const int nB   = ((127 - x) >> 2) + 1;
  const int T    = nA + nB;          // == 33 for all x

  // ---- Q fragments (both tiles) with fused RoPE + scale ----
  bf16x8 aqA[2], aqB[2];
#pragma unroll
  for (int tt = 0; tt < 2; ++tt) {
    const int q0w_t = tt ? q0wB : q0wA;
    const int spos = q0w_t + m;
    const bf16_t* qsrc = QKVb + (size_t)(b * S_ + spos) * NQKV + h * DH_;
    float2 l8[8];
#pragma unroll
    for (int j = 0; j < 8; ++j) l8[j] = lut[spos * 32 + quad * 8 + j];
#pragma unroll
    for (int kc = 0; kc < 2; ++kc) {
      bf16x8 xv = *(const bf16x8*)(qsrc + kc * 32 + quad * 8);
      bf16x8 y;
#pragma unroll
      for (int i = 0; i < 4; ++i) {
        const float x0 = (float)xv[2*i], x1 = (float)xv[2*i+1];
        y[2*i]   = (bf16_t)((x0 * l8[2*i].x   - x1 * l8[2*i].y)   * QSCALE);
        y[2*i+1] = (bf16_t)((x1 * l8[2*i+1].x + x0 * l8[2*i+1].y) * QSCALE);
      }
      if (tt) aqB[kc] = y; else aqA[kc] = y;
    }
  }

  f32x4 oaccA[4], oaccB[4];
#pragma unroll
  for (int d = 0; d < 4; ++d) {
    oaccA[d] = (f32x4){0.f,0.f,0.f,0.f};
    oaccB[d] = (f32x4){0.f,0.f,0.f,0.f};
  }
  float lpA = 0.f, lpB = 0.f;

  const size_t imgbase = ((size_t)(b * NKV_ + kvh) * 32) * 4096;
  const bf16_t* Kg = Kt2 + imgbase;
  const f16_t*  Vg = Vt2 + imgbase;
  const int x0s = quad ^ (m & 7);
  const int x1s = (4 + quad) ^ (m & 7);
  const int* amp = amask + b * S_;

  // prologue: group g stages its first element (e = g)
  int mcur;
  {
    const int e0  = g;
    const int kt0 = (e0 >= nA) ? e0 - nA : e0;
    const size_t off = (size_t)kt0 * 4096;
    gl_lds16(Kg + off + (2*wl)   * 512 + lane * 8, &Ks[g][0][(2*wl)   * 512]);
    gl_lds16(Kg + off + (2*wl+1) * 512 + lane * 8, &Ks[g][0][(2*wl+1) * 512]);
    gl_lds16(Vg + off + (2*wl)   * 512 + lane * 8, &Vs[g][0][(2*wl)   * 512]);
    gl_lds16(Vg + off + (2*wl+1) * 512 + lane * 8, &Vs[g][0][(2*wl+1) * 512]);
    mcur = amp[kt0 * 64 + lane];
  }

  int p = 0;
  const int niter = (T + 1) >> 1;    // 17
  for (int t = 0; t < niter; ++t) {
    const int e = 2 * t + g;
    __syncthreads();                 // drains buf[*][p]'s DMA (issued last iter)
    const int e2 = e + 2;
    const bool more = (e2 < T);
    int kt2 = 0;
    if (more) {
      kt2 = (e2 >= nA) ? e2 - nA : e2;
      const size_t off = (size_t)kt2 * 4096;
      gl_lds16(Kg + off + (2*wl)   * 512 + lane * 8, &Ks[g][p^1][(2*wl)   * 512]);
      gl_lds16(Kg + off + (2*wl+1) * 512 + lane * 8, &Ks[g][p^1][(2*wl+1) * 512]);
      gl_lds16(Vg + off + (2*wl)   * 512 + lane * 8, &Vs[g][p^1][(2*wl)   * 512]);
      gl_lds16(Vg + off + (2*wl+1) * 512 + lane * 8, &Vs[g][p^1][(2*wl+1) * 512]);
    }
    const int mnext = more ? amp[kt2 * 64 + lane] : 0;
    if (e < T) {
      const uint64_t mb = __ballot(mcur != 0);
      const bool isB = (e >= nA);
      const int kt = isB ? e - nA : e;
      const int kbase = kt * 64;
      if (isB) PROC_TILE(aqB, oaccB, lpB, q0wB);
      else     PROC_TILE(aqA, oaccA, lpA, q0wA);
    }
    mcur = mnext;
    p ^= 1;
  }

  // ---- epilogue: cross-group (O,l) merge via LDS (pure adds), store ----
  float lAred = lpA;
  lAred += __shfl_xor(lAred, 16); lAred += __shfl_xor(lAred, 32);
  float lBred = lpB;
  lBred += __shfl_xor(lBred, 16); lBred += __shfl_xor(lBred, 32);

  __syncthreads();                   // all tile compute done; reuse LDS as scratch
  float* scrA = (float*)&Ks[0][0][0];   // 4 heads x 16 rows x 68 floats + l row
  float* scrB = (float*)&Vs[0][0][0];
  const int sbase = wl * 1104 + m * 68 + quad * 4;   // 1104 = 16*68 + 16 pad

  if (g == 0) {
#pragma unroll
    for (int dblk = 0; dblk < 4; ++dblk)
      *(f32x4*)&scrA[sbase + dblk * 16] = oaccA[dblk];
    if (quad == 0) scrA[wl * 1104 + 16 * 68 + m] = lAred;
  } else {
#pragma unroll
    for (int dblk = 0; dblk < 4; ++dblk)
      *(f32x4*)&scrB[sbase + dblk * 16] = oaccB[dblk];
    if (quad == 0) scrB[wl * 1104 + 16 * 68 + m] = lBred;
  }
  __syncthreads();

  if (g == 0) {                      // finalize tile B (add group 1's partial)
    const float l = lBred + scrB[wl * 1104 + 16 * 68 + m];
    const float inv = 1.0f / l;
    const size_t row = (size_t)(b * S_ + q0wB + m);
#pragma unroll
    for (int dblk = 0; dblk < 4; ++dblk) {
      const f32x4 part = *(const f32x4*)&scrB[sbase + dblk * 16];
      bf16x4 o;
      o[0] = (bf16_t)((oaccB[dblk][0] + part[0]) * inv);
      o[1] = (bf16_t)((oaccB[dblk][1] + part[1]) * inv);
      o[2] = (bf16_t)((oaccB[dblk][2] + part[2]) * inv);
      o[3] = (bf16_t)((oaccB[dblk][3] + part[3]) * inv);
      *(bf16x4*)&Ab[row * HID + h * DH_ + dblk * 16 + quad * 4] = o;
    }
  } else {                           // finalize tile A (add group 0's partial)
    const float l = lAred + scrA[wl * 1104 + 16 * 68 + m];
    const float inv = 1.0f / l;
    const size_t row = (size_t)(b * S_ + q0wA + m);
#pragma unroll
    for (int dblk = 0; dblk < 4; ++dblk) {
      const f32x4 part = *(const f32x4*)&scrA[sbase + dblk * 16];
      bf16x4 o;
      o[0] = (bf16_t)((oaccA[dblk][0] + part[0]) * inv);
      o[1] = (bf16_t)((oaccA[dblk][1] + part[1]) * inv);
      o[2] = (bf16_t)((oaccA[dblk][2] + part[2]) * inv);
      o[3] = (bf16_t)((oaccA[dblk][3] + part[3]) * inv);
      *(bf16x4*)&Ab[row * HID + h * DH_ + dblk * 16 + quad * 4] = o;
    }
  }
}

// ---------------------------------------------------------------------------
extern "C" void kernel_launch(void* const* d_in, const int* in_sizes, int n_in,
                              void* d_out, int out_size, void* d_ws, size_t ws_size,
                              hipStream_t stream)
{
  const float* hs    = (const float*)d_in[0];
  const int*   amask = (const int*)  d_in[1];
  const float* Wq    = (const float*)d_in[2];
  const float* bq    = (const float*)d_in[3];
  const float* Wk    = (const float*)d_in[4];
  const float* bk    = (const float*)d_in[5];
  const float* Wv    = (const float*)d_in[6];
  const float* bv    = (const float*)d_in[7];
  const float* Wo    = (const float*)d_in[8];
  const float* bo    = (const float*)d_in[9];
  float* out = (float*)d_out;

  // workspace layout (~31 MB)
  bf16_t* QKVb = (bf16_t*)d_ws;                            // 12.6 MB (live through attn)
  bf16_t* hsb  = QKVb + (size_t)ROWS * NQKV;               // 8 MB (Ab aliases after QKV GEMM)
  bf16_t* Wt   = hsb + (size_t)ROWS * HID;                 // 3 MB
  bf16_t* Wot  = Wt + (size_t)NQKV * HID;                  // 2 MB
  float*  ball = (float*)(Wot + (size_t)HID * HID);        // 6 KB
  bf16_t* Kimg = (bf16_t*)(ball + NQKV);                   // 2 MB
  f16_t*  Vimg = (f16_t*)(Kimg + (size_t)B_*NKV_*32*4096); // 2 MB
  float2* lut  = (float2*)(Vimg + (size_t)B_*NKV_*32*4096);// 0.5 MB
  bf16_t* Ab   = hsb;                                      // alias (hsb dead after QKV GEMM)

  // fused prep: cast + weight transpose + biases + RoPE LUT
  prep_all<<<4870, 256, 0, stream>>>(hs, Wq, Wk, Wv, Wo, bq, bk, bv,
                                     hsb, Wt, Wot, ball, lut);

  // QKV projection + fused K/V image build (RoPE'd K, transposed V)
  gemm_qkv<<<dim3(NQKV/64, ROWS/128), 256, 0, stream>>>(hsb, Wt, ball, lut,
                                                        QKVb, Kimg, Vimg);

  // attention (paired q-tiles, uniform 17 iters/block, raw v_exp_f32)
  attn_v11<<<dim3(64, NKV_, B_), 512, 0, stream>>>(QKVb, lut, Kimg, Vimg, amask, Ab);

  // output projection (512 blocks = 2/CU, dbuf, XCD-chunked swizzle)
  gemm64_f32o<<<dim3(HID/64, ROWS/128), 256, 0, stream>>>(Ab, Wot, bo, out, HID);
}